// Round 11
// baseline (315.714 us; speedup 1.0000x reference)
//
#include <hip/hip_runtime.h>
#include <hip/hip_bf16.h>

#define DIMSZ 1024
#define SEQLEN 4096
#define NHEAD 16
#define NX 16777216L     // x elements
#define NW 1048576L      // weight elements each
#define KVSPLITS 4

typedef __attribute__((ext_vector_type(8))) short bf16x8;
typedef __attribute__((ext_vector_type(4))) float f32x4;

__device__ __forceinline__ unsigned short f2bf(float f) {
    union { float f; unsigned int i; } c; c.f = f;
    unsigned int x = c.i;
    unsigned int r = (x + 0x7fffu + ((x >> 16) & 1u)) >> 16;
    return (unsigned short)r;
}

// pack two f32 -> two bf16 (round-half-up) in one perm
__device__ __forceinline__ unsigned int pk2(float lo, float hi) {
    union { float f; unsigned int i; } a, b; a.f = lo; b.f = hi;
    return __builtin_amdgcn_perm(b.i + 0x8000u, a.i + 0x8000u, 0x07060302u);
}

// register-resident bf16x8 -> 8 floats
__device__ __forceinline__ void unp8r(bf16x8 v, float* f) {
    union { bf16x8 s; uint4 w; } u; u.s = v;
    union { unsigned int i; float f; } c;
    c.i = u.w.x << 16;           f[0] = c.f;
    c.i = u.w.x & 0xffff0000u;   f[1] = c.f;
    c.i = u.w.y << 16;           f[2] = c.f;
    c.i = u.w.y & 0xffff0000u;   f[3] = c.f;
    c.i = u.w.z << 16;           f[4] = c.f;
    c.i = u.w.z & 0xffff0000u;   f[5] = c.f;
    c.i = u.w.w << 16;           f[6] = c.f;
    c.i = u.w.w & 0xffff0000u;   f[7] = c.f;
}

__device__ __forceinline__ void async16(const void* g, void* l) {
    __builtin_amdgcn_global_load_lds(
        (const __attribute__((address_space(1))) void*)g,
        (__attribute__((address_space(3))) void*)l,
        16, 0, 0);
}

// ---------------- kernel 1: weight casts + stdp passthrough ----------------
// x cast is FUSED into qkv_gemm8 (A staged from f32 directly); this kernel
// only converts the 4 weight matrices (12.6 MB, ~4 us).
__global__ __launch_bounds__(256) void cast_pack(
    const float* __restrict__ Wq, const float* __restrict__ Wk,
    const float* __restrict__ Wv, const float* __restrict__ Wo,
    const float* __restrict__ stdp,
    unsigned short* __restrict__ Wqkv, unsigned short* __restrict__ Wob,
    float* __restrict__ outTail)
{
    const long total = NW;   // quads across the 4 weight matrices
    for (long q = (long)blockIdx.x * 256 + threadIdx.x; q < total;
         q += (long)gridDim.x * 256) {
        long i4 = q * 4;
        const float* src; unsigned short* dst; long off;
        if (i4 < NW)           { src = Wq; dst = Wqkv;        off = i4; }
        else if (i4 < 2*NW)    { src = Wk; dst = Wqkv + NW;   off = i4 - NW; }
        else if (i4 < 3*NW)    { src = Wv; dst = Wqkv + 2*NW; off = i4 - 2*NW; }
        else                   { src = Wo; dst = Wob;         off = i4 - 3*NW; }
        float4 v = *(const float4*)(src + off);
        union { unsigned short u[4]; uint2 p; } o;
        o.u[0] = f2bf(v.x); o.u[1] = f2bf(v.y); o.u[2] = f2bf(v.z); o.u[3] = f2bf(v.w);
        *(uint2*)(dst + off) = o.p;
    }
    if (blockIdx.x == 0 && threadIdx.x < NHEAD) outTail[threadIdx.x] = stdp[threadIdx.x];
}

// ---------------- kernel 2: fused QKV GEMM — 256x256 tile, 16 waves --------
// R10 schedule + fused x-cast: A staged from f32 x via reg-staging
// (global f32 load -> pk2 -> ds_write_b128 into the SAME swizzled LDS bytes
// the old global_load_lds path produced). vm issue order per kt:
// [Af32(kt+1) x4 @ top (oldest), B-stage(kt+2) x2 @ mid (newest)] ->
// late vmcnt(2) drains A(kt+1) AND B(kt+1), leaves B(kt+2) in flight
// (R9's failure was stages issued BEFORE the loads they must outlive).
// Tails: kt>=14 -> vmcnt(0). ds_writes covered by end-of-kt lgkmcnt(0)+bar;
// WAR on the written buffer expired at end-of-(kt-1) barrier.
__global__ __launch_bounds__(1024, 1) void qkv_gemm8(
    const float* __restrict__ X, const unsigned short* __restrict__ W,
    const float* __restrict__ bq, const float* __restrict__ bk,
    const float* __restrict__ bv,
    unsigned short* __restrict__ Qb, unsigned short* __restrict__ Kb,
    unsigned short* __restrict__ Vb)
{
    __shared__ __align__(16) char SM[131072];   // 2 bufs x (A 32K + B 32K); reused by epilogue
    const int t = threadIdx.x;
    const int wave = t >> 6, lane = t & 63;
    const int lr = lane & 15, lq = lane >> 4;
    const int wm = wave >> 2, wn = wave & 3;    // wm,wn in 0..3
    const int m0 = blockIdx.x * 256;
    const int c0 = blockIdx.y * 256;

    // staging: LDS dest is linear, so the SOURCE chunk is pre-swizzled.
    const int sc = (((t & 7) ^ ((t >> 3) & 7)) * 8);
    const float* pAx0 = X + (long)(m0 + (t >> 3)) * DIMSZ + sc;   // A half 0 (f32)
    const float* pAx1 = pAx0 + 131072;                            // A half 1 (+128 rows)
    const unsigned short* pB = W + (long)(c0 + (t >> 3)) * DIMSZ + sc;
    char* ldsW = SM + wave * 1024;  // wave-uniform lane base (lane*16 added by HW)

    // ds_read swizzle: frag (row, kchunk = s*4+lq) lives at chunk (kchunk ^ (lr&7))
    const int xo = ((lq ^ (lr & 7)) << 4);
    const char* ABase = SM + wm * 8192 + lr * 128;             // rows wm*64+16i+lr
    const char* BBase = SM + 32768 + (wn * 64 + lr) * 128;     // rows wn*64+16j+lr

    f32x4 acc[4][4];
    #pragma unroll
    for (int i = 0; i < 4; ++i)
        #pragma unroll
        for (int j = 0; j < 4; ++j) acc[i][j] = (f32x4){0.f, 0.f, 0.f, 0.f};

    // B-stage piece H (col-half) of tile Q via global_load_lds (16 KB/inst)
#define STAGEB(Q, H) do {                                                       \
        if ((Q) < 16) {                                                         \
            const unsigned short* s_ = pB + (long)(H) * 131072 + (Q) * 64;      \
            char* d_ = ldsW + (((Q) & 1) << 16) + 32768 + (H) * 16384;          \
            async16(s_, d_);                                                    \
        }                                                                       \
    } while (0)

    // prologue: Af32(0) loads (oldest), then B stages of kt0/kt1
    float4 ax0, ax1, ax2, ax3;
    ax0 = *(const float4*)(pAx0);     ax1 = *(const float4*)(pAx0 + 4);
    ax2 = *(const float4*)(pAx1);     ax3 = *(const float4*)(pAx1 + 4);
    __builtin_amdgcn_sched_barrier(0);
    STAGEB(0, 0); STAGEB(0, 1); STAGEB(1, 0); STAGEB(1, 1);
    __builtin_amdgcn_sched_barrier(0);
    asm volatile("s_waitcnt vmcnt(4)" ::: "memory");   // A(0) landed
    __builtin_amdgcn_sched_barrier(0);
    {
        uint4 w0, w1;
        w0.x = pk2(ax0.x, ax0.y); w0.y = pk2(ax0.z, ax0.w);
        w0.z = pk2(ax1.x, ax1.y); w0.w = pk2(ax1.z, ax1.w);
        w1.x = pk2(ax2.x, ax2.y); w1.y = pk2(ax2.z, ax2.w);
        w1.z = pk2(ax3.x, ax3.y); w1.w = pk2(ax3.z, ax3.w);
        *(uint4*)(SM + t * 16) = w0;              // A(0) half0
        *(uint4*)(SM + 16384 + t * 16) = w1;      // A(0) half1
    }
    asm volatile("s_waitcnt vmcnt(2)" ::: "memory");   // B(0) landed; B(1) in flight
    asm volatile("s_waitcnt lgkmcnt(0)" ::: "memory"); // A(0) writes visible
    __builtin_amdgcn_sched_barrier(0);
    __builtin_amdgcn_s_barrier();

    for (int kt = 0; kt < 16; ++kt) {
        const int buf = (kt & 1) << 16;
        bf16x8 a[4], b[4];

        // ---- top: issue Af32(kt+1) (oldest vm ops of this kt) ----
        if (kt < 15) {
            const float* s0 = pAx0 + (kt + 1) * 64;
            const float* s1 = pAx1 + (kt + 1) * 64;
            ax0 = *(const float4*)(s0); ax1 = *(const float4*)(s0 + 4);
            ax2 = *(const float4*)(s1); ax3 = *(const float4*)(s1 + 4);
        }
        __builtin_amdgcn_sched_barrier(0);

        // ================= K-half 0 (chunks lq) =================
        b[0] = *(const bf16x8*)(BBase + buf + 0 * 2048 + xo);
        b[1] = *(const bf16x8*)(BBase + buf + 1 * 2048 + xo);
        #pragma unroll
        for (int i = 0; i < 4; ++i)
            a[i] = *(const bf16x8*)(ABase + buf + i * 2048 + xo);
        __builtin_amdgcn_sched_barrier(0);
        b[2] = *(const bf16x8*)(BBase + buf + 2 * 2048 + xo);
        b[3] = *(const bf16x8*)(BBase + buf + 3 * 2048 + xo);
        __builtin_amdgcn_sched_barrier(0);

        asm volatile("s_waitcnt lgkmcnt(2)" ::: "memory");   // b0,b1,a0-3 done
        __builtin_amdgcn_sched_barrier(0);
        __builtin_amdgcn_s_setprio(1);
        #pragma unroll
        for (int i = 0; i < 4; ++i)
            #pragma unroll
            for (int j = 0; j < 2; ++j)
                acc[i][j] = __builtin_amdgcn_mfma_f32_16x16x32_bf16(
                    b[j], a[i], acc[i][j], 0, 0, 0);
        __builtin_amdgcn_s_setprio(0);

        asm volatile("s_waitcnt lgkmcnt(0)" ::: "memory");   // b2,b3 done
        __builtin_amdgcn_sched_barrier(0);
        __builtin_amdgcn_s_setprio(1);
        #pragma unroll
        for (int i = 0; i < 4; ++i)
            #pragma unroll
            for (int j = 2; j < 4; ++j)
                acc[i][j] = __builtin_amdgcn_mfma_f32_16x16x32_bf16(
                    b[j], a[i], acc[i][j], 0, 0, 0);
        __builtin_amdgcn_s_setprio(0);

        // ================= K-half 1 (chunks 4+lq -> xo^64) =================
        b[0] = *(const bf16x8*)(BBase + buf + 0 * 2048 + (xo ^ 64));
        b[1] = *(const bf16x8*)(BBase + buf + 1 * 2048 + (xo ^ 64));
        #pragma unroll
        for (int i = 0; i < 4; ++i)
            a[i] = *(const bf16x8*)(ABase + buf + i * 2048 + (xo ^ 64));
        __builtin_amdgcn_sched_barrier(0);
        b[2] = *(const bf16x8*)(BBase + buf + 2 * 2048 + (xo ^ 64));
        b[3] = *(const bf16x8*)(BBase + buf + 3 * 2048 + (xo ^ 64));
        __builtin_amdgcn_sched_barrier(0);

        asm volatile("s_waitcnt lgkmcnt(2)" ::: "memory");
        __builtin_amdgcn_sched_barrier(0);
        __builtin_amdgcn_s_setprio(1);
        #pragma unroll
        for (int i = 0; i < 4; ++i)
            #pragma unroll
            for (int j = 0; j < 2; ++j)
                acc[i][j] = __builtin_amdgcn_mfma_f32_16x16x32_bf16(
                    b[j], a[i], acc[i][j], 0, 0, 0);
        __builtin_amdgcn_s_setprio(0);

        asm volatile("s_waitcnt lgkmcnt(0)" ::: "memory");   // ALL reads of buf done
        __builtin_amdgcn_sched_barrier(0);
        __builtin_amdgcn_s_barrier();            // all waves done reading this buf
        STAGEB(kt + 2, 0); STAGEB(kt + 2, 1);    // newest vm ops

        // late: drain Af32(kt+1) (and B(kt+1)); keep B(kt+2) in flight
        if (kt < 14)  asm volatile("s_waitcnt vmcnt(2)" ::: "memory");
        else          asm volatile("s_waitcnt vmcnt(0)" ::: "memory");
        __builtin_amdgcn_sched_barrier(0);
        if (kt < 15) {
            uint4 w0, w1;
            w0.x = pk2(ax0.x, ax0.y); w0.y = pk2(ax0.z, ax0.w);
            w0.z = pk2(ax1.x, ax1.y); w0.w = pk2(ax1.z, ax1.w);
            w1.x = pk2(ax2.x, ax2.y); w1.y = pk2(ax2.z, ax2.w);
            w1.z = pk2(ax3.x, ax3.y); w1.w = pk2(ax3.z, ax3.w);
            const int nbuf = ((kt + 1) & 1) << 16;
            *(uint4*)(SM + nbuf + t * 16) = w0;           // A(kt+1) half0
            *(uint4*)(SM + nbuf + 16384 + t * 16) = w1;   // A(kt+1) half1
        }
        __builtin_amdgcn_sched_barrier(0);

        // last quadrant: register-only; overlaps the ds_writes
        __builtin_amdgcn_s_setprio(1);
        #pragma unroll
        for (int i = 0; i < 4; ++i)
            #pragma unroll
            for (int j = 2; j < 4; ++j)
                acc[i][j] = __builtin_amdgcn_mfma_f32_16x16x32_bf16(
                    b[j], a[i], acc[i][j], 0, 0, 0);
        __builtin_amdgcn_s_setprio(0);

        asm volatile("s_waitcnt lgkmcnt(0)" ::: "memory");   // A(kt+1) writes done
        __builtin_amdgcn_sched_barrier(0);
        __builtin_amdgcn_s_barrier();
    }
#undef STAGEB

    // ---- epilogue: bias + elu+1 + pack, swizzled LDS transpose, stores ----
    const int proj = c0 >> 10;                         // block-uniform
    const float* bias = proj == 0 ? bq : (proj == 1 ? bk : bv);
    const bool qk = proj < 2;
    const int cb = (c0 & 1023) + wn * 64;
    const int q4 = lq * 4;
    #pragma unroll
    for (int j = 0; j < 4; ++j) {
        const float4 b4 = *(const float4*)(bias + cb + 16 * j + q4);
        #pragma unroll
        for (int i = 0; i < 4; ++i) {
            float v0 = acc[i][j][0] + b4.x, v1 = acc[i][j][1] + b4.y;
            float v2 = acc[i][j][2] + b4.z, v3 = acc[i][j][3] + b4.w;
            if (qk) {
                v0 = v0 > 0.f ? v0 + 1.f : __expf(v0);
                v1 = v1 > 0.f ? v1 + 1.f : __expf(v1);
                v2 = v2 > 0.f ? v2 + 1.f : __expf(v2);
                v3 = v3 > 0.f ? v3 + 1.f : __expf(v3);
            }
            const int row = wm * 64 + 16 * i + lr;
            int byte = row * 512 + wn * 128 + j * 32 + q4 * 2;
            byte ^= (row & 7) << 4;
            uint2 pkd; pkd.x = pk2(v0, v1); pkd.y = pk2(v2, v3);
            *(uint2*)(SM + byte) = pkd;
        }
    }
    __syncthreads();
    unsigned short* dstp = proj == 0 ? Qb : (proj == 1 ? Kb : Vb);
    const int colsh = (t & 31) * 8;                    // tile-local col (shorts)
    const int h = ((c0 >> 6) + (colsh >> 6)) & 15;
    const int b_ = m0 >> 12;
    unsigned short* dbase = dstp + ((long)(b_ * 16 + h) * SEQLEN) * 64 + (colsh & 63);
    #pragma unroll
    for (int u = 0; u < 8; ++u) {
        const int flat = u * 16384 + t * 16;
        const int row = flat >> 9;
        uint4 val = *(const uint4*)(SM + (flat ^ ((row & 7) << 4)));
        const int n = (m0 + row) & 4095;
        *(uint4*)(dbase + (long)n * 64) = val;
    }
}

// ---------------- kernel 3: KV partials + Ksum partials via MFMA ----------
// splits=4; each block folds 1024 rows in four 256-row LDS passes,
// accumulator carried across. Transposed swizzled staging; swapped-op mfma.
__global__ __launch_bounds__(256) void kv_reduce(
    const unsigned short* __restrict__ Kb, const unsigned short* __restrict__ Vb,
    float* __restrict__ KVp, float* __restrict__ Ksump)
{
    __shared__ __align__(16) char LDS[65536];   // 2 iters x (Kt 16K + Vt 16K)
    int bh = blockIdx.x, split = blockIdx.y, t = threadIdx.x;
    int wave = t >> 6, lane = t & 63, lr = lane & 15, lq = lane >> 4;

    const int nl = t & 127;            // local n row this thread stages
    const int dh = (t >> 7) * 32;      // d-half (wave-uniform)
    const int vrow = 16 * wave + lr;

    f32x4 acc[4];
    #pragma unroll
    for (int j = 0; j < 4; ++j) acc[j] = (f32x4){0.f, 0.f, 0.f, 0.f};
    float ksp[4] = {0.f, 0.f, 0.f, 0.f};

    for (int pass = 0; pass < SEQLEN / KVSPLITS / 256; ++pass) {
        const unsigned short* Kbase = Kb + ((long)bh * SEQLEN + split * (SEQLEN / KVSPLITS) + pass * 256) * 64;
        const unsigned short* Vbase = Vb + ((long)bh * SEQLEN + split * (SEQLEN / KVSPLITS) + pass * 256) * 64;

        union Q2S { uint4 q[4]; unsigned short s[32]; };
        Q2S kq[2], vq[2];
        #pragma unroll
        for (int it = 0; it < 2; ++it) {
            const unsigned short* kp = Kbase + (long)(it * 128 + nl) * 64 + dh;
            const unsigned short* vp = Vbase + (long)(it * 128 + nl) * 64 + dh;
            #pragma unroll
            for (int g = 0; g < 4; ++g) {
                kq[it].q[g] = *(const uint4*)(kp + g * 8);
                vq[it].q[g] = *(const uint4*)(vp + g * 8);
            }
        }
        if (pass) __syncthreads();   // prior pass's reads complete before overwrite
        // transposed swizzled stores: elem (n=nl, d=dh+e) at d*256 + (2n ^ ((d&7)<<4))
        #pragma unroll
        for (int it = 0; it < 2; ++it) {
            char* buf = LDS + it * 32768;
            #pragma unroll
            for (int e = 0; e < 32; ++e) {
                const int d = dh + e;
                const int a = d * 256 + ((nl * 2) ^ ((d & 7) << 4));
                *(unsigned short*)(buf + a) = kq[it].s[e];
                *(unsigned short*)(buf + 16384 + a) = vq[it].s[e];
            }
        }
        __syncthreads();

        #pragma unroll
        for (int it = 0; it < 2; ++it) {
            const char* buf = LDS + it * 32768;
            #pragma unroll
            for (int ns = 0; ns < 4; ++ns) {
                const int xoff = (ns * 64 + lq * 16) ^ ((lr & 7) << 4);
                bf16x8 af = *(const bf16x8*)(buf + 16384 + vrow * 256 + xoff);
                bf16x8 bfr[4];
                #pragma unroll
                for (int j = 0; j < 4; ++j)
                    bfr[j] = *(const bf16x8*)(buf + (16 * j + lr) * 256 + xoff);
                if (wave == 0) {
                    #pragma unroll
                    for (int j = 0; j < 4; ++j) {
                        float kf[8]; unp8r(bfr[j], kf);
                        ksp[j] += ((kf[0] + kf[1]) + (kf[2] + kf[3]))
                                + ((kf[4] + kf[5]) + (kf[6] + kf[7]));
                    }
                }
                #pragma unroll
                for (int j = 0; j < 4; ++j)
                    acc[j] = __builtin_amdgcn_mfma_f32_16x16x32_bf16(bfr[j], af, acc[j], 0, 0, 0);
            }
        }
    }

    float* kp = KVp + ((long)split * 64 + bh) * 4096;
    const int q4 = lq * 4;
    #pragma unroll
    for (int j = 0; j < 4; ++j)
        *(f32x4*)(kp + vrow * 64 + 16 * j + q4) = acc[j];

    if (wave == 0) {
        #pragma unroll
        for (int j = 0; j < 4; ++j) {
            float s = ksp[j];
            s += __shfl_xor(s, 16);
            s += __shfl_xor(s, 32);
            if (lane < 16)
                Ksump[((long)split * 64 + bh) * 64 + 16 * j + lr] = s;
        }
    }
}

// ---------------- kernel 3b: fold partials -> KV bf16 + Ksum f32 ----------
__global__ __launch_bounds__(256) void kv_final(
    const float* __restrict__ KVp, const float* __restrict__ Ksump,
    unsigned short* __restrict__ KVb, float* __restrict__ Ksum)
{
    int bh = blockIdx.x, t = threadIdx.x;
    float s[16];
    #pragma unroll
    for (int g = 0; g < 16; ++g) s[g] = 0.f;
    for (int sp = 0; sp < KVSPLITS; ++sp) {
        const float* src = KVp + ((long)sp * 64 + bh) * 4096 + t * 16;
        #pragma unroll
        for (int g = 0; g < 4; ++g) {
            float4 v = *(const float4*)(src + g * 4);
            s[g * 4 + 0] += v.x; s[g * 4 + 1] += v.y;
            s[g * 4 + 2] += v.z; s[g * 4 + 3] += v.w;
        }
    }
    uint4 o0, o1;
    o0.x = pk2(s[0], s[1]);  o0.y = pk2(s[2], s[3]);
    o0.z = pk2(s[4], s[5]);  o0.w = pk2(s[6], s[7]);
    o1.x = pk2(s[8], s[9]);  o1.y = pk2(s[10], s[11]);
    o1.z = pk2(s[12], s[13]); o1.w = pk2(s[14], s[15]);
    *(uint4*)(KVb + (long)bh * 4096 + t * 16) = o0;
    *(uint4*)(KVb + (long)bh * 4096 + t * 16 + 8) = o1;
    if (t < 16) {
        float4 a = {0.f, 0.f, 0.f, 0.f};
        #pragma unroll
        for (int p = 0; p < KVSPLITS; ++p) {
            float4 v = *(const float4*)(Ksump + ((long)p * 64 + bh) * 64 + t * 4);
            a.x += v.x; a.y += v.y; a.z += v.z; a.w += v.w;
        }
        *(float4*)(Ksum + bh * 64 + t * 4) = a;
    }
}

// ---------------- kernel 4: numerator MFMA + fused denominator -> attn bf16
__global__ __launch_bounds__(256) void attn_kernel(
    const unsigned short* __restrict__ Qb, const unsigned short* __restrict__ KVb,
    const float* __restrict__ Ksum, const float* __restrict__ stdp,
    unsigned short* __restrict__ attn)
{
    __shared__ unsigned short Cs[256 * 72];   // output staging
    int t = threadIdx.x;
    int bh = blockIdx.y;   // 64
    int b = bh >> 4, h = bh & 15;

    int wave = t >> 6, lane = t & 63, lr = lane & 15, lk = (lane >> 4) * 8;
    const unsigned short* kvb = KVb + (long)bh * 4096;
    const float* ksb = Ksum + bh * 64;

    // hoist KV fragments + Ksum slices (block-invariant)
    bf16x8 bfrh[2][4];
    float ksf[2][8];
    #pragma unroll
    for (int s = 0; s < 2; ++s) {
        #pragma unroll
        for (int j = 0; j < 4; ++j)
            bfrh[s][j] = *(const bf16x8*)(kvb + (16 * j + lr) * 64 + s * 32 + lk);
        float4 ka = *(const float4*)(ksb + s * 32 + lk);
        float4 kb2 = *(const float4*)(ksb + s * 32 + lk + 4);
        ksf[s][0] = ka.x; ksf[s][1] = ka.y; ksf[s][2] = ka.z; ksf[s][3] = ka.w;
        ksf[s][4] = kb2.x; ksf[s][5] = kb2.y; ksf[s][6] = kb2.z; ksf[s][7] = kb2.w;
    }
    float sg = 1.f / (1.f + __expf(-stdp[h]));
    int q4 = (lane >> 4) * 4;

    for (int c = 0; c < 2; ++c) {
        int rc = blockIdx.x * 2 + c;
        int rowbase = rc * 256 + wave * 64;

        f32x4 acc[4][4];
        #pragma unroll
        for (int i = 0; i < 4; ++i)
            #pragma unroll
            for (int j = 0; j < 4; ++j) acc[i][j] = (f32x4){0.f, 0.f, 0.f, 0.f};
        float ds[4] = {0.f, 0.f, 0.f, 0.f};

        #pragma unroll
        for (int s = 0; s < 2; ++s) {
            bf16x8 af[4];
            #pragma unroll
            for (int i = 0; i < 4; ++i)
                af[i] = *(const bf16x8*)(Qb + ((long)bh * SEQLEN + rowbase + 16 * i + lr) * 64 + s * 32 + lk);
            #pragma unroll
            for (int i = 0; i < 4; ++i) {
                float qf[8]; unp8r(af[i], qf);
                #pragma unroll
                for (int e = 0; e < 8; ++e) ds[i] += qf[e] * ksf[s][e];
            }
            #pragma unroll
            for (int i = 0; i < 4; ++i)
                #pragma unroll
                for (int j = 0; j < 4; ++j)
                    acc[i][j] = __builtin_amdgcn_mfma_f32_16x16x32_bf16(bfrh[s][j], af[i], acc[i][j], 0, 0, 0);
        }

        float dinv_i[4];
        #pragma unroll
        for (int i = 0; i < 4; ++i) {
            float d = ds[i];
            d += __shfl_xor(d, 16);
            d += __shfl_xor(d, 32);
            dinv_i[i] = sg / (d + 1e-6f);
        }

        #pragma unroll
        for (int j = 0; j < 4; ++j) {
            int v0c = 16 * j + q4;
            #pragma unroll
            for (int i = 0; i < 4; ++i) {
                int row = wave * 64 + 16 * i + lr;
                float d = dinv_i[i];
                uint2 pkd;
                pkd.x = pk2(acc[i][j][0] * d, acc[i][j][1] * d);
                pkd.y = pk2(acc[i][j][2] * d, acc[i][j][3] * d);
                *(uint2*)(Cs + row * 72 + v0c) = pkd;
            }
        }
        __syncthreads();
        #pragma unroll
        for (int u = 0; u < 8; ++u) {
            int row = u * 32 + (t >> 3);
            int nn = rc * 256 + row;
            long a = ((long)(b * SEQLEN + nn)) * DIMSZ + h * 64 + (t & 7) * 8;
            *(uint4*)(attn + a) = *(const uint4*)(Cs + row * 72 + (t & 7) * 8);
        }
        __syncthreads();   // Cs reuse across chunks
    }
}

// ---------------- kernel 5: output GEMM — 256x256 tile, 16 waves ----------
// same 16-wave counted-lgkm structure (bf16 A from workspace); epilogue f32.
__global__ __launch_bounds__(1024, 1) void out_gemm8(
    const unsigned short* __restrict__ A, const unsigned short* __restrict__ W,
    const float* __restrict__ bo, float* __restrict__ out)
{
    __shared__ __align__(16) char SM[131072];
    const int t = threadIdx.x;
    const int wave = t >> 6, lane = t & 63;
    const int lr = lane & 15, lq = lane >> 4;
    const int wm = wave >> 2, wn = wave & 3;
    const int m0 = blockIdx.x * 256;
    const int c0 = blockIdx.y * 256;

    const int sc = (((t & 7) ^ ((t >> 3) & 7)) * 8);
    const unsigned short* pA = A + (long)(m0 + (t >> 3)) * DIMSZ + sc;
    const unsigned short* pB = W + (long)(c0 + (t >> 3)) * DIMSZ + sc;
    char* ldsW = SM + wave * 1024;

    const int xo = ((lq ^ (lr & 7)) << 4);
    const char* ABase = SM + wm * 8192 + lr * 128;
    const char* BBase = SM + 32768 + (wn * 64 + lr) * 128;

    f32x4 acc[4][4];
    #pragma unroll
    for (int i = 0; i < 4; ++i)
        #pragma unroll
        for (int j = 0; j < 4; ++j) acc[i][j] = (f32x4){0.f, 0.f, 0.f, 0.f};

#define STAGE(Q, O) do {                                                        \
        if ((Q) < 16) {                                                         \
            const int isB_ = ((O) < 2) ? 1 : 0;                                 \
            const int half_ = isB_ ? (O) : ((O) - 2);                           \
            const unsigned short* s_ = (isB_ ? pB : pA)                         \
                                       + (long)half_ * 131072 + (Q) * 64;       \
            char* d_ = ldsW + (((Q) & 1) << 16) + isB_ * 32768 + half_ * 16384; \
            async16(s_, d_);                                                    \
        }                                                                       \
    } while (0)

    STAGE(0, 0); STAGE(0, 1); STAGE(0, 2); STAGE(0, 3);
    STAGE(1, 0); STAGE(1, 1); STAGE(1, 2);
    asm volatile("s_waitcnt vmcnt(3)" ::: "memory");
    __builtin_amdgcn_s_barrier();

    for (int kt = 0; kt < 16; ++kt) {
        const int buf = (kt & 1) << 16;
        bf16x8 a[4], b[4];

        // K-half 0
        b[0] = *(const bf16x8*)(BBase + buf + 0 * 2048 + xo);
        b[1] = *(const bf16x8*)(BBase + buf + 1 * 2048 + xo);
        #pragma unroll
        for (int i = 0; i < 4; ++i)
            a[i] = *(const bf16x8*)(ABase + buf + i * 2048 + xo);
        __builtin_amdgcn_sched_barrier(0);
        b[2] = *(const bf16x8*)(BBase + buf + 2 * 2048 + xo);
        b[3] = *(const bf16x8*)(BBase + buf + 3 * 2048 + xo);
        __builtin_amdgcn_sched_barrier(0);
        STAGE(kt + 1, 3);

        asm volatile("s_waitcnt lgkmcnt(2)" ::: "memory");
        __builtin_amdgcn_sched_barrier(0);
        __builtin_amdgcn_s_setprio(1);
        #pragma unroll
        for (int i = 0; i < 4; ++i)
            #pragma unroll
            for (int j = 0; j < 2; ++j)
                acc[i][j] = __builtin_amdgcn_mfma_f32_16x16x32_bf16(
                    b[j], a[i], acc[i][j], 0, 0, 0);
        __builtin_amdgcn_s_setprio(0);

        asm volatile("s_waitcnt lgkmcnt(0)" ::: "memory");
        __builtin_amdgcn_sched_barrier(0);
        __builtin_amdgcn_s_setprio(1);
        #pragma unroll
        for (int i = 0; i < 4; ++i)
            #pragma unroll
            for (int j = 2; j < 4; ++j)
                acc[i][j] = __builtin_amdgcn_mfma_f32_16x16x32_bf16(
                    b[j], a[i], acc[i][j], 0, 0, 0);
        __builtin_amdgcn_s_setprio(0);

        // K-half 1
        b[0] = *(const bf16x8*)(BBase + buf + 0 * 2048 + (xo ^ 64));
        b[1] = *(const bf16x8*)(BBase + buf + 1 * 2048 + (xo ^ 64));
        #pragma unroll
        for (int i = 0; i < 4; ++i)
            a[i] = *(const bf16x8*)(ABase + buf + i * 2048 + (xo ^ 64));
        __builtin_amdgcn_sched_barrier(0);
        b[2] = *(const bf16x8*)(BBase + buf + 2 * 2048 + (xo ^ 64));
        b[3] = *(const bf16x8*)(BBase + buf + 3 * 2048 + (xo ^ 64));
        __builtin_amdgcn_sched_barrier(0);

        asm volatile("s_waitcnt lgkmcnt(2)" ::: "memory");
        __builtin_amdgcn_sched_barrier(0);
        __builtin_amdgcn_s_setprio(1);
        #pragma unroll
        for (int i = 0; i < 4; ++i)
            #pragma unroll
            for (int j = 0; j < 2; ++j)
                acc[i][j] = __builtin_amdgcn_mfma_f32_16x16x32_bf16(
                    b[j], a[i], acc[i][j], 0, 0, 0);
        __builtin_amdgcn_s_setprio(0);

        asm volatile("s_waitcnt lgkmcnt(0)" ::: "memory");
        __builtin_amdgcn_sched_barrier(0);
        __builtin_amdgcn_s_barrier();
        STAGE(kt + 2, 0); STAGE(kt + 2, 1); STAGE(kt + 2, 2);

        __builtin_amdgcn_s_setprio(1);
        #pragma unroll
        for (int i = 0; i < 4; ++i)
            #pragma unroll
            for (int j = 2; j < 4; ++j)
                acc[i][j] = __builtin_amdgcn_mfma_f32_16x16x32_bf16(
                    b[j], a[i], acc[i][j], 0, 0, 0);
        __builtin_amdgcn_s_setprio(0);

        if (kt < 14)       asm volatile("s_waitcnt vmcnt(3)" ::: "memory");
        else if (kt == 14) asm volatile("s_waitcnt vmcnt(0)" ::: "memory");
        __builtin_amdgcn_s_barrier();
    }
#undef STAGE

    const int q4 = lq * 4;
    #pragma unroll
    for (int j = 0; j < 4; ++j) {
        const int c = c0 + wn * 64 + 16 * j + q4;
        const float4 b4 = *(const float4*)(bo + c);
        #pragma unroll
        for (int i = 0; i < 4; ++i) {
            const int gm = m0 + wm * 64 + 16 * i + lr;
            float4 v;
            v.x = acc[i][j][0] + b4.x; v.y = acc[i][j][1] + b4.y;
            v.z = acc[i][j][2] + b4.z; v.w = acc[i][j][3] + b4.w;
            *(float4*)(out + (long)gm * DIMSZ + c) = v;
        }
    }
}

extern "C" void kernel_launch(void* const* d_in, const int* in_sizes, int n_in,
                              void* d_out, int out_size, void* d_ws, size_t ws_size,
                              hipStream_t stream) {
    const float* x    = (const float*)d_in[0];
    const float* Wq   = (const float*)d_in[1];
    const float* bq   = (const float*)d_in[2];
    const float* Wk   = (const float*)d_in[3];
    const float* bk   = (const float*)d_in[4];
    const float* Wv   = (const float*)d_in[5];
    const float* bv   = (const float*)d_in[6];
    const float* Wo   = (const float*)d_in[7];
    const float* bo   = (const float*)d_in[8];
    const float* stdp = (const float*)d_in[9];
    float* out = (float*)d_out;

    char* ws = (char*)d_ws;
    float*          KVp  = (float*)(ws);                          // 4.2 MB
    unsigned short* attn = (unsigned short*)(ws);                 // 32 MB
    unsigned short* Wqkv = (unsigned short*)(ws + 33554432L);     // 6 MB
    float*          Ksump= (float*)(ws + 33554432L);              // 64 KB
    unsigned short* KVb  = (unsigned short*)(ws + 33816576L);     // 512 KB
    float*          Ksum = (float*)(ws + 34340864L);              // 16 KB
    unsigned short* Wob  = (unsigned short*)(ws + 39845888L);     // 2 MB
    unsigned short* Qb   = (unsigned short*)(ws + 41943040L);     // 32 MB
    unsigned short* Kb   = (unsigned short*)(ws + 75497472L);     // 32 MB
    unsigned short* Vb   = (unsigned short*)(ws + 109051904L);    // 32 MB

    cast_pack<<<1024, 256, 0, stream>>>(Wq, Wk, Wv, Wo, stdp, Wqkv, Wob,
                                        out + 16777216L);
    qkv_gemm8<<<dim3(64, 12), 1024, 0, stream>>>(x, Wqkv, bq, bk, bv, Qb, Kb, Vb);
    kv_reduce<<<dim3(64, KVSPLITS), 256, 0, stream>>>(Kb, Vb, KVp, Ksump);
    kv_final<<<64, 256, 0, stream>>>(KVp, Ksump, KVb, Ksum);
    attn_kernel<<<dim3(8, 64), 256, 0, stream>>>(Qb, KVb, Ksum, stdp, attn);
    out_gemm8<<<dim3(64, 4), 1024, 0, stream>>>(attn, Wob, bo, out);
}

// Round 12
// 309.996 us; speedup vs baseline: 1.0184x; 1.0184x over previous
//
#include <hip/hip_runtime.h>
#include <hip/hip_bf16.h>

#define DIMSZ 1024
#define SEQLEN 4096
#define NHEAD 16
#define NX 16777216L     // x elements
#define NW 1048576L      // weight elements each
#define KVSPLITS 4

typedef __attribute__((ext_vector_type(8))) short bf16x8;
typedef __attribute__((ext_vector_type(4))) float f32x4;

__device__ __forceinline__ unsigned short f2bf(float f) {
    union { float f; unsigned int i; } c; c.f = f;
    unsigned int x = c.i;
    unsigned int r = (x + 0x7fffu + ((x >> 16) & 1u)) >> 16;
    return (unsigned short)r;
}

// pack two f32 -> two bf16 (round-half-up) in one perm
__device__ __forceinline__ unsigned int pk2(float lo, float hi) {
    union { float f; unsigned int i; } a, b; a.f = lo; b.f = hi;
    return __builtin_amdgcn_perm(b.i + 0x8000u, a.i + 0x8000u, 0x07060302u);
}

// register-resident bf16x8 -> 8 floats
__device__ __forceinline__ void unp8r(bf16x8 v, float* f) {
    union { bf16x8 s; uint4 w; } u; u.s = v;
    union { unsigned int i; float f; } c;
    c.i = u.w.x << 16;           f[0] = c.f;
    c.i = u.w.x & 0xffff0000u;   f[1] = c.f;
    c.i = u.w.y << 16;           f[2] = c.f;
    c.i = u.w.y & 0xffff0000u;   f[3] = c.f;
    c.i = u.w.z << 16;           f[4] = c.f;
    c.i = u.w.z & 0xffff0000u;   f[5] = c.f;
    c.i = u.w.w << 16;           f[6] = c.f;
    c.i = u.w.w & 0xffff0000u;   f[7] = c.f;
}

__device__ __forceinline__ void async16(const void* g, void* l) {
    __builtin_amdgcn_global_load_lds(
        (const __attribute__((address_space(1))) void*)g,
        (__attribute__((address_space(3))) void*)l,
        16, 0, 0);
}

// ---------------- kernel 1: weight casts + stdp passthrough ----------------
__global__ __launch_bounds__(256) void cast_pack(
    const float* __restrict__ Wq, const float* __restrict__ Wk,
    const float* __restrict__ Wv, const float* __restrict__ Wo,
    const float* __restrict__ stdp,
    unsigned short* __restrict__ Wqkv, unsigned short* __restrict__ Wob,
    float* __restrict__ outTail)
{
    const long total = NW;   // quads across the 4 weight matrices
    for (long q = (long)blockIdx.x * 256 + threadIdx.x; q < total;
         q += (long)gridDim.x * 256) {
        long i4 = q * 4;
        const float* src; unsigned short* dst; long off;
        if (i4 < NW)           { src = Wq; dst = Wqkv;        off = i4; }
        else if (i4 < 2*NW)    { src = Wk; dst = Wqkv + NW;   off = i4 - NW; }
        else if (i4 < 3*NW)    { src = Wv; dst = Wqkv + 2*NW; off = i4 - 2*NW; }
        else                   { src = Wo; dst = Wob;         off = i4 - 3*NW; }
        float4 v = *(const float4*)(src + off);
        union { unsigned short u[4]; uint2 p; } o;
        o.u[0] = f2bf(v.x); o.u[1] = f2bf(v.y); o.u[2] = f2bf(v.z); o.u[3] = f2bf(v.w);
        *(uint2*)(dst + off) = o.p;
    }
    if (blockIdx.x == 0 && threadIdx.x < NHEAD) outTail[threadIdx.x] = stdp[threadIdx.x];
}

// ---------------- kernel 2: fused QKV GEMM — 256x256 tile, 16 waves --------
// Fused x-cast v2: the A pack+ds_write block is placed INSIDE the K-half-1
// MFMA window (R11 put it in the serial post-barrier tail -> +33 us).
// vm order per kt: A-f32(kt+1)x4 at top (oldest), STAGEB(kt+2)x2 at tail
// (newest). Mid-half1 vmcnt(0) drains A + the >=1kt-old B(kt+1) stages; no
// tail vmcnt needed. lgkm in half1: 6 reads, 2 reads, 2 writes -> gates
// lgkmcnt(4) (Q10), lgkmcnt(2) (Q11), lgkmcnt(0) before end barrier (writes
// visible). kt=15 clamps the A load (in-bounds) and writes a dead region so
// the lgkm constants stay uniform.
__global__ __launch_bounds__(1024, 1) void qkv_gemm8(
    const float* __restrict__ X, const unsigned short* __restrict__ W,
    const float* __restrict__ bq, const float* __restrict__ bk,
    const float* __restrict__ bv,
    unsigned short* __restrict__ Qb, unsigned short* __restrict__ Kb,
    unsigned short* __restrict__ Vb)
{
    __shared__ __align__(16) char SM[131072];   // 2 bufs x (A 32K + B 32K); reused by epilogue
    const int t = threadIdx.x;
    const int wave = t >> 6, lane = t & 63;
    const int lr = lane & 15, lq = lane >> 4;
    const int wm = wave >> 2, wn = wave & 3;    // wm,wn in 0..3
    const int m0 = blockIdx.x * 256;
    const int c0 = blockIdx.y * 256;

    // staging: LDS dest is linear, so the SOURCE chunk is pre-swizzled.
    const int sc = (((t & 7) ^ ((t >> 3) & 7)) * 8);
    const float* pAx0 = X + (long)(m0 + (t >> 3)) * DIMSZ + sc;   // A half 0 (f32)
    const float* pAx1 = pAx0 + 131072;                            // A half 1 (+128 rows)
    const unsigned short* pB = W + (long)(c0 + (t >> 3)) * DIMSZ + sc;
    char* ldsW = SM + wave * 1024;  // wave-uniform lane base (lane*16 added by HW)

    // ds_read swizzle: frag (row, kchunk = s*4+lq) lives at chunk (kchunk ^ (lr&7))
    const int xo = ((lq ^ (lr & 7)) << 4);
    const char* ABase = SM + wm * 8192 + lr * 128;             // rows wm*64+16i+lr
    const char* BBase = SM + 32768 + (wn * 64 + lr) * 128;     // rows wn*64+16j+lr

    f32x4 acc[4][4];
    #pragma unroll
    for (int i = 0; i < 4; ++i)
        #pragma unroll
        for (int j = 0; j < 4; ++j) acc[i][j] = (f32x4){0.f, 0.f, 0.f, 0.f};

    // B-stage piece H (col-half) of tile Q via global_load_lds (16 KB/inst)
#define STAGEB(Q, H) do {                                                       \
        if ((Q) < 16) {                                                         \
            const unsigned short* s_ = pB + (long)(H) * 131072 + (Q) * 64;      \
            char* d_ = ldsW + (((Q) & 1) << 16) + 32768 + (H) * 16384;          \
            async16(s_, d_);                                                    \
        }                                                                       \
    } while (0)

    // prologue: Af32(0) loads (oldest), then B stages of kt0/kt1
    float4 ax0, ax1, ax2, ax3;
    ax0 = *(const float4*)(pAx0);     ax1 = *(const float4*)(pAx0 + 4);
    ax2 = *(const float4*)(pAx1);     ax3 = *(const float4*)(pAx1 + 4);
    __builtin_amdgcn_sched_barrier(0);
    STAGEB(0, 0); STAGEB(0, 1); STAGEB(1, 0); STAGEB(1, 1);
    __builtin_amdgcn_sched_barrier(0);
    asm volatile("s_waitcnt vmcnt(4)" ::: "memory");   // A(0) landed
    __builtin_amdgcn_sched_barrier(0);
    {
        uint4 w0, w1;
        w0.x = pk2(ax0.x, ax0.y); w0.y = pk2(ax0.z, ax0.w);
        w0.z = pk2(ax1.x, ax1.y); w0.w = pk2(ax1.z, ax1.w);
        w1.x = pk2(ax2.x, ax2.y); w1.y = pk2(ax2.z, ax2.w);
        w1.z = pk2(ax3.x, ax3.y); w1.w = pk2(ax3.z, ax3.w);
        *(uint4*)(SM + t * 16) = w0;              // A(0) half0
        *(uint4*)(SM + 16384 + t * 16) = w1;      // A(0) half1
    }
    asm volatile("s_waitcnt vmcnt(2)" ::: "memory");   // B(0) landed; B(1) in flight
    asm volatile("s_waitcnt lgkmcnt(0)" ::: "memory"); // A(0) writes visible
    __builtin_amdgcn_sched_barrier(0);
    __builtin_amdgcn_s_barrier();

    for (int kt = 0; kt < 16; ++kt) {
        const int buf = (kt & 1) << 16;
        bf16x8 a[4], b[4];

        // ---- top: issue Af32 for next kt (clamped at kt=15; oldest vm ops)
        {
            const int ktn = (kt < 15) ? kt + 1 : 15;
            const float* s0 = pAx0 + ktn * 64;
            const float* s1 = pAx1 + ktn * 64;
            ax0 = *(const float4*)(s0); ax1 = *(const float4*)(s0 + 4);
            ax2 = *(const float4*)(s1); ax3 = *(const float4*)(s1 + 4);
        }
        __builtin_amdgcn_sched_barrier(0);

        // ================= K-half 0 (chunks lq) =================
        b[0] = *(const bf16x8*)(BBase + buf + 0 * 2048 + xo);
        b[1] = *(const bf16x8*)(BBase + buf + 1 * 2048 + xo);
        #pragma unroll
        for (int i = 0; i < 4; ++i)
            a[i] = *(const bf16x8*)(ABase + buf + i * 2048 + xo);
        __builtin_amdgcn_sched_barrier(0);
        b[2] = *(const bf16x8*)(BBase + buf + 2 * 2048 + xo);
        b[3] = *(const bf16x8*)(BBase + buf + 3 * 2048 + xo);
        __builtin_amdgcn_sched_barrier(0);

        asm volatile("s_waitcnt lgkmcnt(2)" ::: "memory");   // b0,b1,a0-3 done
        __builtin_amdgcn_sched_barrier(0);
        __builtin_amdgcn_s_setprio(1);
        #pragma unroll
        for (int i = 0; i < 4; ++i) {
            acc[i][0] = __builtin_amdgcn_mfma_f32_16x16x32_bf16(b[0], a[i], acc[i][0], 0, 0, 0);
            acc[i][1] = __builtin_amdgcn_mfma_f32_16x16x32_bf16(b[1], a[i], acc[i][1], 0, 0, 0);
        }
        __builtin_amdgcn_s_setprio(0);

        asm volatile("s_waitcnt lgkmcnt(0)" ::: "memory");   // b2,b3 done
        __builtin_amdgcn_sched_barrier(0);
        __builtin_amdgcn_s_setprio(1);
        #pragma unroll
        for (int i = 0; i < 4; ++i) {
            acc[i][2] = __builtin_amdgcn_mfma_f32_16x16x32_bf16(b[2], a[i], acc[i][2], 0, 0, 0);
            acc[i][3] = __builtin_amdgcn_mfma_f32_16x16x32_bf16(b[3], a[i], acc[i][3], 0, 0, 0);
        }
        __builtin_amdgcn_s_setprio(0);

        // ================= K-half 1 (chunks 4+lq -> xo^64) =================
        b[0] = *(const bf16x8*)(BBase + buf + 0 * 2048 + (xo ^ 64));
        b[1] = *(const bf16x8*)(BBase + buf + 1 * 2048 + (xo ^ 64));
        #pragma unroll
        for (int i = 0; i < 4; ++i)
            a[i] = *(const bf16x8*)(ABase + buf + i * 2048 + (xo ^ 64));
        __builtin_amdgcn_sched_barrier(0);
        b[2] = *(const bf16x8*)(BBase + buf + 2 * 2048 + (xo ^ 64));
        b[3] = *(const bf16x8*)(BBase + buf + 3 * 2048 + (xo ^ 64));
        __builtin_amdgcn_sched_barrier(0);

        // ---- A pack + swizzled ds_write into buffer[(kt+1)&1] A-region ----
        // (reads of that region expired at end-of-(kt-1) barrier)
        asm volatile("s_waitcnt vmcnt(0)" ::: "memory");   // A loads (+old B stages) done
        __builtin_amdgcn_sched_barrier(0);
        {
            uint4 w0, w1;
            w0.x = pk2(ax0.x, ax0.y); w0.y = pk2(ax0.z, ax0.w);
            w0.z = pk2(ax1.x, ax1.y); w0.w = pk2(ax1.z, ax1.w);
            w1.x = pk2(ax2.x, ax2.y); w1.y = pk2(ax2.z, ax2.w);
            w1.z = pk2(ax3.x, ax3.y); w1.w = pk2(ax3.z, ax3.w);
            const int nbuf = ((kt + 1) & 1) << 16;
            *(uint4*)(SM + nbuf + t * 16) = w0;           // A(next) half0
            *(uint4*)(SM + nbuf + 16384 + t * 16) = w1;   // A(next) half1
        }
        __builtin_amdgcn_sched_barrier(0);

        asm volatile("s_waitcnt lgkmcnt(4)" ::: "memory");   // b0,b1,a done (b2,b3,w fly)
        __builtin_amdgcn_sched_barrier(0);
        __builtin_amdgcn_s_setprio(1);
        #pragma unroll
        for (int i = 0; i < 4; ++i) {
            acc[i][0] = __builtin_amdgcn_mfma_f32_16x16x32_bf16(b[0], a[i], acc[i][0], 0, 0, 0);
            acc[i][1] = __builtin_amdgcn_mfma_f32_16x16x32_bf16(b[1], a[i], acc[i][1], 0, 0, 0);
        }
        __builtin_amdgcn_s_setprio(0);

        asm volatile("s_waitcnt lgkmcnt(2)" ::: "memory");   // b2,b3 done (writes fly)
        __builtin_amdgcn_sched_barrier(0);
        __builtin_amdgcn_s_barrier();            // all waves done reading this buf
        STAGEB(kt + 2, 0); STAGEB(kt + 2, 1);    // overwrite current buf's B (newest vm)

        __builtin_amdgcn_s_setprio(1);
        #pragma unroll
        for (int i = 0; i < 4; ++i) {
            acc[i][2] = __builtin_amdgcn_mfma_f32_16x16x32_bf16(b[2], a[i], acc[i][2], 0, 0, 0);
            acc[i][3] = __builtin_amdgcn_mfma_f32_16x16x32_bf16(b[3], a[i], acc[i][3], 0, 0, 0);
        }
        __builtin_amdgcn_s_setprio(0);

        asm volatile("s_waitcnt lgkmcnt(0)" ::: "memory");   // A(next) writes visible
        __builtin_amdgcn_sched_barrier(0);
        __builtin_amdgcn_s_barrier();
    }
#undef STAGEB

    // ---- epilogue: bias + elu+1 + pack, swizzled LDS transpose, stores ----
    const int proj = c0 >> 10;                         // block-uniform
    const float* bias = proj == 0 ? bq : (proj == 1 ? bk : bv);
    const bool qk = proj < 2;
    const int cb = (c0 & 1023) + wn * 64;
    const int q4 = lq * 4;
    #pragma unroll
    for (int j = 0; j < 4; ++j) {
        const float4 b4 = *(const float4*)(bias + cb + 16 * j + q4);
        #pragma unroll
        for (int i = 0; i < 4; ++i) {
            float v0 = acc[i][j][0] + b4.x, v1 = acc[i][j][1] + b4.y;
            float v2 = acc[i][j][2] + b4.z, v3 = acc[i][j][3] + b4.w;
            if (qk) {
                v0 = v0 > 0.f ? v0 + 1.f : __expf(v0);
                v1 = v1 > 0.f ? v1 + 1.f : __expf(v1);
                v2 = v2 > 0.f ? v2 + 1.f : __expf(v2);
                v3 = v3 > 0.f ? v3 + 1.f : __expf(v3);
            }
            const int row = wm * 64 + 16 * i + lr;
            int byte = row * 512 + wn * 128 + j * 32 + q4 * 2;
            byte ^= (row & 7) << 4;
            uint2 pkd; pkd.x = pk2(v0, v1); pkd.y = pk2(v2, v3);
            *(uint2*)(SM + byte) = pkd;
        }
    }
    __syncthreads();
    unsigned short* dstp = proj == 0 ? Qb : (proj == 1 ? Kb : Vb);
    const int colsh = (t & 31) * 8;                    // tile-local col (shorts)
    const int h = ((c0 >> 6) + (colsh >> 6)) & 15;
    const int b_ = m0 >> 12;
    unsigned short* dbase = dstp + ((long)(b_ * 16 + h) * SEQLEN) * 64 + (colsh & 63);
    #pragma unroll
    for (int u = 0; u < 8; ++u) {
        const int flat = u * 16384 + t * 16;
        const int row = flat >> 9;
        uint4 val = *(const uint4*)(SM + (flat ^ ((row & 7) << 4)));
        const int n = (m0 + row) & 4095;
        *(uint4*)(dbase + (long)n * 64) = val;
    }
}

// ---------------- kernel 3: KV partials + Ksum partials via MFMA ----------
// splits=4; each block folds 1024 rows in four 256-row LDS passes,
// accumulator carried across. Transposed swizzled staging; swapped-op mfma.
__global__ __launch_bounds__(256) void kv_reduce(
    const unsigned short* __restrict__ Kb, const unsigned short* __restrict__ Vb,
    float* __restrict__ KVp, float* __restrict__ Ksump)
{
    __shared__ __align__(16) char LDS[65536];   // 2 iters x (Kt 16K + Vt 16K)
    int bh = blockIdx.x, split = blockIdx.y, t = threadIdx.x;
    int wave = t >> 6, lane = t & 63, lr = lane & 15, lq = lane >> 4;

    const int nl = t & 127;            // local n row this thread stages
    const int dh = (t >> 7) * 32;      // d-half (wave-uniform)
    const int vrow = 16 * wave + lr;

    f32x4 acc[4];
    #pragma unroll
    for (int j = 0; j < 4; ++j) acc[j] = (f32x4){0.f, 0.f, 0.f, 0.f};
    float ksp[4] = {0.f, 0.f, 0.f, 0.f};

    for (int pass = 0; pass < SEQLEN / KVSPLITS / 256; ++pass) {
        const unsigned short* Kbase = Kb + ((long)bh * SEQLEN + split * (SEQLEN / KVSPLITS) + pass * 256) * 64;
        const unsigned short* Vbase = Vb + ((long)bh * SEQLEN + split * (SEQLEN / KVSPLITS) + pass * 256) * 64;

        union Q2S { uint4 q[4]; unsigned short s[32]; };
        Q2S kq[2], vq[2];
        #pragma unroll
        for (int it = 0; it < 2; ++it) {
            const unsigned short* kp = Kbase + (long)(it * 128 + nl) * 64 + dh;
            const unsigned short* vp = Vbase + (long)(it * 128 + nl) * 64 + dh;
            #pragma unroll
            for (int g = 0; g < 4; ++g) {
                kq[it].q[g] = *(const uint4*)(kp + g * 8);
                vq[it].q[g] = *(const uint4*)(vp + g * 8);
            }
        }
        if (pass) __syncthreads();   // prior pass's reads complete before overwrite
        // transposed swizzled stores: elem (n=nl, d=dh+e) at d*256 + (2n ^ ((d&7)<<4))
        #pragma unroll
        for (int it = 0; it < 2; ++it) {
            char* buf = LDS + it * 32768;
            #pragma unroll
            for (int e = 0; e < 32; ++e) {
                const int d = dh + e;
                const int a = d * 256 + ((nl * 2) ^ ((d & 7) << 4));
                *(unsigned short*)(buf + a) = kq[it].s[e];
                *(unsigned short*)(buf + 16384 + a) = vq[it].s[e];
            }
        }
        __syncthreads();

        #pragma unroll
        for (int it = 0; it < 2; ++it) {
            const char* buf = LDS + it * 32768;
            #pragma unroll
            for (int ns = 0; ns < 4; ++ns) {
                const int xoff = (ns * 64 + lq * 16) ^ ((lr & 7) << 4);
                bf16x8 af = *(const bf16x8*)(buf + 16384 + vrow * 256 + xoff);
                bf16x8 bfr[4];
                #pragma unroll
                for (int j = 0; j < 4; ++j)
                    bfr[j] = *(const bf16x8*)(buf + (16 * j + lr) * 256 + xoff);
                if (wave == 0) {
                    #pragma unroll
                    for (int j = 0; j < 4; ++j) {
                        float kf[8]; unp8r(bfr[j], kf);
                        ksp[j] += ((kf[0] + kf[1]) + (kf[2] + kf[3]))
                                + ((kf[4] + kf[5]) + (kf[6] + kf[7]));
                    }
                }
                #pragma unroll
                for (int j = 0; j < 4; ++j)
                    acc[j] = __builtin_amdgcn_mfma_f32_16x16x32_bf16(bfr[j], af, acc[j], 0, 0, 0);
            }
        }
    }

    float* kp = KVp + ((long)split * 64 + bh) * 4096;
    const int q4 = lq * 4;
    #pragma unroll
    for (int j = 0; j < 4; ++j)
        *(f32x4*)(kp + vrow * 64 + 16 * j + q4) = acc[j];

    if (wave == 0) {
        #pragma unroll
        for (int j = 0; j < 4; ++j) {
            float s = ksp[j];
            s += __shfl_xor(s, 16);
            s += __shfl_xor(s, 32);
            if (lane < 16)
                Ksump[((long)split * 64 + bh) * 64 + 16 * j + lr] = s;
        }
    }
}

// ---------------- kernel 3b: fold partials -> KV bf16 + Ksum f32 ----------
__global__ __launch_bounds__(256) void kv_final(
    const float* __restrict__ KVp, const float* __restrict__ Ksump,
    unsigned short* __restrict__ KVb, float* __restrict__ Ksum)
{
    int bh = blockIdx.x, t = threadIdx.x;
    float s[16];
    #pragma unroll
    for (int g = 0; g < 16; ++g) s[g] = 0.f;
    for (int sp = 0; sp < KVSPLITS; ++sp) {
        const float* src = KVp + ((long)sp * 64 + bh) * 4096 + t * 16;
        #pragma unroll
        for (int g = 0; g < 4; ++g) {
            float4 v = *(const float4*)(src + g * 4);
            s[g * 4 + 0] += v.x; s[g * 4 + 1] += v.y;
            s[g * 4 + 2] += v.z; s[g * 4 + 3] += v.w;
        }
    }
    uint4 o0, o1;
    o0.x = pk2(s[0], s[1]);  o0.y = pk2(s[2], s[3]);
    o0.z = pk2(s[4], s[5]);  o0.w = pk2(s[6], s[7]);
    o1.x = pk2(s[8], s[9]);  o1.y = pk2(s[10], s[11]);
    o1.z = pk2(s[12], s[13]); o1.w = pk2(s[14], s[15]);
    *(uint4*)(KVb + (long)bh * 4096 + t * 16) = o0;
    *(uint4*)(KVb + (long)bh * 4096 + t * 16 + 8) = o1;
    if (t < 16) {
        float4 a = {0.f, 0.f, 0.f, 0.f};
        #pragma unroll
        for (int p = 0; p < KVSPLITS; ++p) {
            float4 v = *(const float4*)(Ksump + ((long)p * 64 + bh) * 64 + t * 4);
            a.x += v.x; a.y += v.y; a.z += v.z; a.w += v.w;
        }
        *(float4*)(Ksum + bh * 64 + t * 4) = a;
    }
}

// ---------------- kernel 4: numerator MFMA + fused denominator -> attn bf16
__global__ __launch_bounds__(256) void attn_kernel(
    const unsigned short* __restrict__ Qb, const unsigned short* __restrict__ KVb,
    const float* __restrict__ Ksum, const float* __restrict__ stdp,
    unsigned short* __restrict__ attn)
{
    __shared__ unsigned short Cs[256 * 72];   // output staging
    int t = threadIdx.x;
    int bh = blockIdx.y;   // 64
    int b = bh >> 4, h = bh & 15;

    int wave = t >> 6, lane = t & 63, lr = lane & 15, lk = (lane >> 4) * 8;
    const unsigned short* kvb = KVb + (long)bh * 4096;
    const float* ksb = Ksum + bh * 64;

    // hoist KV fragments + Ksum slices (block-invariant)
    bf16x8 bfrh[2][4];
    float ksf[2][8];
    #pragma unroll
    for (int s = 0; s < 2; ++s) {
        #pragma unroll
        for (int j = 0; j < 4; ++j)
            bfrh[s][j] = *(const bf16x8*)(kvb + (16 * j + lr) * 64 + s * 32 + lk);
        float4 ka = *(const float4*)(ksb + s * 32 + lk);
        float4 kb2 = *(const float4*)(ksb + s * 32 + lk + 4);
        ksf[s][0] = ka.x; ksf[s][1] = ka.y; ksf[s][2] = ka.z; ksf[s][3] = ka.w;
        ksf[s][4] = kb2.x; ksf[s][5] = kb2.y; ksf[s][6] = kb2.z; ksf[s][7] = kb2.w;
    }
    float sg = 1.f / (1.f + __expf(-stdp[h]));
    int q4 = (lane >> 4) * 4;

    for (int c = 0; c < 2; ++c) {
        int rc = blockIdx.x * 2 + c;
        int rowbase = rc * 256 + wave * 64;

        f32x4 acc[4][4];
        #pragma unroll
        for (int i = 0; i < 4; ++i)
            #pragma unroll
            for (int j = 0; j < 4; ++j) acc[i][j] = (f32x4){0.f, 0.f, 0.f, 0.f};
        float ds[4] = {0.f, 0.f, 0.f, 0.f};

        #pragma unroll
        for (int s = 0; s < 2; ++s) {
            bf16x8 af[4];
            #pragma unroll
            for (int i = 0; i < 4; ++i)
                af[i] = *(const bf16x8*)(Qb + ((long)bh * SEQLEN + rowbase + 16 * i + lr) * 64 + s * 32 + lk);
            #pragma unroll
            for (int i = 0; i < 4; ++i) {
                float qf[8]; unp8r(af[i], qf);
                #pragma unroll
                for (int e = 0; e < 8; ++e) ds[i] += qf[e] * ksf[s][e];
            }
            #pragma unroll
            for (int i = 0; i < 4; ++i)
                #pragma unroll
                for (int j = 0; j < 4; ++j)
                    acc[i][j] = __builtin_amdgcn_mfma_f32_16x16x32_bf16(bfrh[s][j], af[i], acc[i][j], 0, 0, 0);
        }

        float dinv_i[4];
        #pragma unroll
        for (int i = 0; i < 4; ++i) {
            float d = ds[i];
            d += __shfl_xor(d, 16);
            d += __shfl_xor(d, 32);
            dinv_i[i] = sg / (d + 1e-6f);
        }

        #pragma unroll
        for (int j = 0; j < 4; ++j) {
            int v0c = 16 * j + q4;
            #pragma unroll
            for (int i = 0; i < 4; ++i) {
                int row = wave * 64 + 16 * i + lr;
                float d = dinv_i[i];
                uint2 pkd;
                pkd.x = pk2(acc[i][j][0] * d, acc[i][j][1] * d);
                pkd.y = pk2(acc[i][j][2] * d, acc[i][j][3] * d);
                *(uint2*)(Cs + row * 72 + v0c) = pkd;
            }
        }
        __syncthreads();
        #pragma unroll
        for (int u = 0; u < 8; ++u) {
            int row = u * 32 + (t >> 3);
            int nn = rc * 256 + row;
            long a = ((long)(b * SEQLEN + nn)) * DIMSZ + h * 64 + (t & 7) * 8;
            *(uint4*)(attn + a) = *(const uint4*)(Cs + row * 72 + (t & 7) * 8);
        }
        __syncthreads();   // Cs reuse across chunks
    }
}

// ---------------- kernel 5: output GEMM — 256x256 tile, 16 waves ----------
// same 16-wave counted-lgkm structure (bf16 A from workspace); epilogue f32.
__global__ __launch_bounds__(1024, 1) void out_gemm8(
    const unsigned short* __restrict__ A, const unsigned short* __restrict__ W,
    const float* __restrict__ bo, float* __restrict__ out)
{
    __shared__ __align__(16) char SM[131072];
    const int t = threadIdx.x;
    const int wave = t >> 6, lane = t & 63;
    const int lr = lane & 15, lq = lane >> 4;
    const int wm = wave >> 2, wn = wave & 3;
    const int m0 = blockIdx.x * 256;
    const int c0 = blockIdx.y * 256;

    const int sc = (((t & 7) ^ ((t >> 3) & 7)) * 8);
    const unsigned short* pA = A + (long)(m0 + (t >> 3)) * DIMSZ + sc;
    const unsigned short* pB = W + (long)(c0 + (t >> 3)) * DIMSZ + sc;
    char* ldsW = SM + wave * 1024;

    const int xo = ((lq ^ (lr & 7)) << 4);
    const char* ABase = SM + wm * 8192 + lr * 128;
    const char* BBase = SM + 32768 + (wn * 64 + lr) * 128;

    f32x4 acc[4][4];
    #pragma unroll
    for (int i = 0; i < 4; ++i)
        #pragma unroll
        for (int j = 0; j < 4; ++j) acc[i][j] = (f32x4){0.f, 0.f, 0.f, 0.f};

#define STAGE(Q, O) do {                                                        \
        if ((Q) < 16) {                                                         \
            const int isB_ = ((O) < 2) ? 1 : 0;                                 \
            const int half_ = isB_ ? (O) : ((O) - 2);                           \
            const unsigned short* s_ = (isB_ ? pB : pA)                         \
                                       + (long)half_ * 131072 + (Q) * 64;       \
            char* d_ = ldsW + (((Q) & 1) << 16) + isB_ * 32768 + half_ * 16384; \
            async16(s_, d_);                                                    \
        }                                                                       \
    } while (0)

    STAGE(0, 0); STAGE(0, 1); STAGE(0, 2); STAGE(0, 3);
    STAGE(1, 0); STAGE(1, 1); STAGE(1, 2);
    asm volatile("s_waitcnt vmcnt(3)" ::: "memory");
    __builtin_amdgcn_s_barrier();

    for (int kt = 0; kt < 16; ++kt) {
        const int buf = (kt & 1) << 16;
        bf16x8 a[4], b[4];

        // K-half 0
        b[0] = *(const bf16x8*)(BBase + buf + 0 * 2048 + xo);
        b[1] = *(const bf16x8*)(BBase + buf + 1 * 2048 + xo);
        #pragma unroll
        for (int i = 0; i < 4; ++i)
            a[i] = *(const bf16x8*)(ABase + buf + i * 2048 + xo);
        __builtin_amdgcn_sched_barrier(0);
        b[2] = *(const bf16x8*)(BBase + buf + 2 * 2048 + xo);
        b[3] = *(const bf16x8*)(BBase + buf + 3 * 2048 + xo);
        __builtin_amdgcn_sched_barrier(0);
        STAGE(kt + 1, 3);

        asm volatile("s_waitcnt lgkmcnt(2)" ::: "memory");
        __builtin_amdgcn_sched_barrier(0);
        __builtin_amdgcn_s_setprio(1);
        #pragma unroll
        for (int i = 0; i < 4; ++i)
            #pragma unroll
            for (int j = 0; j < 2; ++j)
                acc[i][j] = __builtin_amdgcn_mfma_f32_16x16x32_bf16(
                    b[j], a[i], acc[i][j], 0, 0, 0);
        __builtin_amdgcn_s_setprio(0);

        asm volatile("s_waitcnt lgkmcnt(0)" ::: "memory");
        __builtin_amdgcn_sched_barrier(0);
        __builtin_amdgcn_s_setprio(1);
        #pragma unroll
        for (int i = 0; i < 4; ++i)
            #pragma unroll
            for (int j = 2; j < 4; ++j)
                acc[i][j] = __builtin_amdgcn_mfma_f32_16x16x32_bf16(
                    b[j], a[i], acc[i][j], 0, 0, 0);
        __builtin_amdgcn_s_setprio(0);

        // K-half 1
        b[0] = *(const bf16x8*)(BBase + buf + 0 * 2048 + (xo ^ 64));
        b[1] = *(const bf16x8*)(BBase + buf + 1 * 2048 + (xo ^ 64));
        #pragma unroll
        for (int i = 0; i < 4; ++i)
            a[i] = *(const bf16x8*)(ABase + buf + i * 2048 + (xo ^ 64));
        __builtin_amdgcn_sched_barrier(0);
        b[2] = *(const bf16x8*)(BBase + buf + 2 * 2048 + (xo ^ 64));
        b[3] = *(const bf16x8*)(BBase + buf + 3 * 2048 + (xo ^ 64));
        __builtin_amdgcn_sched_barrier(0);

        asm volatile("s_waitcnt lgkmcnt(2)" ::: "memory");
        __builtin_amdgcn_sched_barrier(0);
        __builtin_amdgcn_s_setprio(1);
        #pragma unroll
        for (int i = 0; i < 4; ++i)
            #pragma unroll
            for (int j = 0; j < 2; ++j)
                acc[i][j] = __builtin_amdgcn_mfma_f32_16x16x32_bf16(
                    b[j], a[i], acc[i][j], 0, 0, 0);
        __builtin_amdgcn_s_setprio(0);

        asm volatile("s_waitcnt lgkmcnt(0)" ::: "memory");
        __builtin_amdgcn_sched_barrier(0);
        __builtin_amdgcn_s_barrier();
        STAGE(kt + 2, 0); STAGE(kt + 2, 1); STAGE(kt + 2, 2);

        __builtin_amdgcn_s_setprio(1);
        #pragma unroll
        for (int i = 0; i < 4; ++i)
            #pragma unroll
            for (int j = 2; j < 4; ++j)
                acc[i][j] = __builtin_amdgcn_mfma_f32_16x16x32_bf16(
                    b[j], a[i], acc[i][j], 0, 0, 0);
        __builtin_amdgcn_s_setprio(0);

        if (kt < 14)       asm volatile("s_waitcnt vmcnt(3)" ::: "memory");
        else if (kt == 14) asm volatile("s_waitcnt vmcnt(0)" ::: "memory");
        __builtin_amdgcn_s_barrier();
    }
#undef STAGE

    const int q4 = lq * 4;
    #pragma unroll
    for (int j = 0; j < 4; ++j) {
        const int c = c0 + wn * 64 + 16 * j + q4;
        const float4 b4 = *(const float4*)(bo + c);
        #pragma unroll
        for (int i = 0; i < 4; ++i) {
            const int gm = m0 + wm * 64 + 16 * i + lr;
            float4 v;
            v.x = acc[i][j][0] + b4.x; v.y = acc[i][j][1] + b4.y;
            v.z = acc[i][j][2] + b4.z; v.w = acc[i][j][3] + b4.w;
            *(float4*)(out + (long)gm * DIMSZ + c) = v;
        }
    }
}

extern "C" void kernel_launch(void* const* d_in, const int* in_sizes, int n_in,
                              void* d_out, int out_size, void* d_ws, size_t ws_size,
                              hipStream_t stream) {
    const float* x    = (const float*)d_in[0];
    const float* Wq   = (const float*)d_in[1];
    const float* bq   = (const float*)d_in[2];
    const float* Wk   = (const float*)d_in[3];
    const float* bk   = (const float*)d_in[4];
    const float* Wv   = (const float*)d_in[5];
    const float* bv   = (const float*)d_in[6];
    const float* Wo   = (const float*)d_in[7];
    const float* bo   = (const float*)d_in[8];
    const float* stdp = (const float*)d_in[9];
    float* out = (float*)d_out;

    char* ws = (char*)d_ws;
    float*          KVp  = (float*)(ws);                          // 4.2 MB
    unsigned short* attn = (unsigned short*)(ws);                 // 32 MB
    unsigned short* Wqkv = (unsigned short*)(ws + 33554432L);     // 6 MB
    float*          Ksump= (float*)(ws + 33554432L);              // 64 KB
    unsigned short* KVb  = (unsigned short*)(ws + 33816576L);     // 512 KB
    float*          Ksum = (float*)(ws + 34340864L);              // 16 KB
    unsigned short* Wob  = (unsigned short*)(ws + 39845888L);     // 2 MB
    unsigned short* Qb   = (unsigned short*)(ws + 41943040L);     // 32 MB
    unsigned short* Kb   = (unsigned short*)(ws + 75497472L);     // 32 MB
    unsigned short* Vb   = (unsigned short*)(ws + 109051904L);    // 32 MB

    cast_pack<<<1024, 256, 0, stream>>>(Wq, Wk, Wv, Wo, stdp, Wqkv, Wob,
                                        out + 16777216L);
    qkv_gemm8<<<dim3(64, 12), 1024, 0, stream>>>(x, Wqkv, bq, bk, bv, Qb, Kb, Vb);
    kv_reduce<<<dim3(64, KVSPLITS), 256, 0, stream>>>(Kb, Vb, KVp, Ksump);
    kv_final<<<64, 256, 0, stream>>>(KVp, Ksump, KVb, Ksum);
    attn_kernel<<<dim3(8, 64), 256, 0, stream>>>(Qb, KVb, Ksum, stdp, attn);
    out_gemm8<<<dim3(64, 4), 1024, 0, stream>>>(attn, Wob, bo, out);
}